// Round 1
// baseline (1095.373 us; speedup 1.0000x reference)
//
#include <hip/hip_runtime.h>
#include <stdint.h>

// Problem constants
//   B=2, N=2048, C=1024, H=16, D=64, 3C=3072
#define LOGMAX 4.605170185988091f  // log(100)
#define LOG2E  1.44269504f

typedef __attribute__((ext_vector_type(4))) float f32x4;
typedef __attribute__((ext_vector_type(8))) short s16x8;   // 8 bf16 (4 VGPRs)
typedef __attribute__((ext_vector_type(4))) unsigned short u16x4;
typedef unsigned short bh16;

__device__ __forceinline__ bh16 f2bf(float f) {
  union { float f; uint32_t u; } c; c.f = f;
  uint32_t u = c.u;
  u += 0x7fffu + ((u >> 16) & 1u);   // round-to-nearest-even
  return (bh16)(u >> 16);
}

__device__ __forceinline__ void async16(const void* g, void* l) {
  __builtin_amdgcn_global_load_lds((const __attribute__((address_space(1))) void*)g,
                                   (__attribute__((address_space(3))) void*)l, 16, 0, 0);
}

__device__ __forceinline__ f32x4 mfma_bf16(s16x8 a, s16x8 b, f32x4 c) {
  return __builtin_amdgcn_mfma_f32_16x16x32_bf16(a, b, c, 0, 0, 0);
}

// ---------------------------------------------------------------------------
// Kernel 0: fp32 -> bf16 casts for x (4M), qkv_w (3M), proj_w (1M)
//   + mask -> log2-domain additive bias maskl2[b*2048+k] in {0, -1e30}
// ---------------------------------------------------------------------------
__global__ __launch_bounds__(256) void cast_kernel(
    const float* __restrict__ x, const float* __restrict__ wq, const float* __restrict__ wp,
    const int* __restrict__ mask,
    bh16* __restrict__ xb, bh16* __restrict__ wqb, bh16* __restrict__ wpb,
    float* __restrict__ maskl2) {
  int i = blockIdx.x * 256 + threadIdx.x;           // chunk of 4 floats
  if (i >= 2097152) {                               // mask chunks: 1024 of 4
    int j = i - 2097152;
    int4 m4 = *(const int4*)(mask + j * 4);
    f32x4 o;
    o[0] = m4.x ? -1.0e30f : 0.0f;
    o[1] = m4.y ? -1.0e30f : 0.0f;
    o[2] = m4.z ? -1.0e30f : 0.0f;
    o[3] = m4.w ? -1.0e30f : 0.0f;
    *(f32x4*)(maskl2 + j * 4) = o;
    return;
  }
  const float* s; bh16* d; int j;
  if (i < 1048576)      { s = x;  d = xb;  j = i; }
  else if (i < 1835008) { s = wq; d = wqb; j = i - 1048576; }
  else                  { s = wp; d = wpb; j = i - 1835008; }
  f32x4 v = *(const f32x4*)(s + (size_t)j * 4);
  u16x4 o;
  o[0] = f2bf(v[0]); o[1] = f2bf(v[1]); o[2] = f2bf(v[2]); o[3] = f2bf(v[3]);
  *(u16x4*)(d + (size_t)j * 4) = o;
}

// ---------------------------------------------------------------------------
// Kernel 1: QKV GEMM (NT): out3c[m][n'] = sum_k x[m][k]*W[n'][k]
//   M=4096 tokens, N'=3072, K=1024. 128x128 tile, BK=32, 256 thr (4 waves).
//   Epilogue: q,k rows L2-normalized -> Qn/Kn [bh][n][d] bf16,
//             v transposed -> Vt [bh][d][n] bf16.
// ---------------------------------------------------------------------------
__global__ __launch_bounds__(256) void qkv_kernel(
    const bh16* __restrict__ xb, const bh16* __restrict__ wqb,
    bh16* __restrict__ Qn, bh16* __restrict__ Kn, bh16* __restrict__ Vt) {
  __shared__ bh16 smem[18432];          // staging 16 KB; epilogue 36 KB (reused)
  bh16* As = smem;                      // [128][32] bf16
  bh16* Bs = smem + 4096;               // [128][32]
  const int tid = threadIdx.x;
  const int wave = tid >> 6, lane = tid & 63;
  const int l15 = lane & 15, g = lane >> 4;
  const int m0 = blockIdx.x * 128;      // token rows
  const int n0 = blockIdx.y * 128;      // 3C cols
  const int wm = (wave & 1) * 64, wn = (wave >> 1) * 64;

  f32x4 acc[4][4] = {};

  for (int k0 = 0; k0 < 1024; k0 += 32) {
#pragma unroll
    for (int r = 0; r < 2; ++r) {
      int chunk = r * 256 + tid;                // 512 chunks of 16 B per tile
      int row = chunk >> 2, ko = chunk & 3;
      async16(xb  + (size_t)(m0 + row) * 1024 + k0 + ko * 8, (void*)(As + chunk * 8));
      async16(wqb + (size_t)(n0 + row) * 1024 + k0 + ko * 8, (void*)(Bs + chunk * 8));
    }
    __syncthreads();
    s16x8 af[4], bfv[4];
#pragma unroll
    for (int i = 0; i < 4; ++i) af[i]  = *(const s16x8*)(As + (wm + i * 16 + l15) * 32 + g * 8);
#pragma unroll
    for (int i = 0; i < 4; ++i) bfv[i] = *(const s16x8*)(Bs + (wn + i * 16 + l15) * 32 + g * 8);
#pragma unroll
    for (int mi = 0; mi < 4; ++mi)
#pragma unroll
      for (int ni = 0; ni < 4; ++ni)
        acc[mi][ni] = mfma_bf16(af[mi], bfv[ni], acc[mi][ni]);
    __syncthreads();
  }

  // epilogue — wave-private LDS repack buffer [64][72] bf16
  bh16* ep = smem + wave * 4608;
  const int part = n0 >> 10;                    // 0=q 1=k 2=v
  const int h = ((n0 + wn) & 1023) >> 6;
  const int b = m0 >> 11;
  const int tok0 = (m0 & 2047) + wm;
  const int bh = b * 16 + h;

  if (part < 2) {
#pragma unroll
    for (int mi = 0; mi < 4; ++mi) {
#pragma unroll
      for (int r = 0; r < 4; ++r) {
        float ss = 0.f;
#pragma unroll
        for (int ni = 0; ni < 4; ++ni) { float v = acc[mi][ni][r]; ss += v * v; }
        ss += __shfl_xor(ss, 1, 64);
        ss += __shfl_xor(ss, 2, 64);
        ss += __shfl_xor(ss, 4, 64);
        ss += __shfl_xor(ss, 8, 64);
        float rn = rsqrtf(ss);
#pragma unroll
        for (int ni = 0; ni < 4; ++ni)
          ep[(mi * 16 + g * 4 + r) * 72 + ni * 16 + l15] = f2bf(acc[mi][ni][r] * rn);
      }
    }
    bh16* dst = (part == 0 ? Qn : Kn) + ((size_t)bh * 2048 + tok0) * 64;
#pragma unroll
    for (int j = 0; j < 8; ++j) {
      int chunk = j * 64 + lane;
      int row = chunk >> 3, cc = chunk & 7;
      *(s16x8*)(dst + chunk * 8) = *(const s16x8*)(ep + row * 72 + cc * 8);
    }
  } else {
#pragma unroll
    for (int mi = 0; mi < 4; ++mi)
#pragma unroll
      for (int r = 0; r < 4; ++r)
#pragma unroll
        for (int ni = 0; ni < 4; ++ni)
          ep[(ni * 16 + l15) * 72 + mi * 16 + g * 4 + r] = f2bf(acc[mi][ni][r]);
#pragma unroll
    for (int j = 0; j < 8; ++j) {
      int chunk = j * 64 + lane;
      int drow = chunk >> 3, cc = chunk & 7;
      *(s16x8*)(Vt + ((size_t)bh * 64 + drow) * 2048 + tok0 + cc * 8) =
          *(const s16x8*)(ep + drow * 72 + cc * 8);
    }
  }
}

// ---------------------------------------------------------------------------
// Kernel 2: flash attention, S^T formulation — barrier-free version.
//   Block = 1-D, XCD-swizzled: bh pinned to one XCD so K/V (512 KB/bh,
//   4 bh/XCD = 2 MB) stay L2-resident; K/V fragments read DIRECTLY from
//   global (L1/L2) — no LDS staging, no __syncthreads, no vmcnt(0) drains.
//   Softmax in log2 domain (scale2 = scale*log2e, alibi pre-scaled, mask as
//   additive -1e30), T13 defer-max (THR=11.5 ~ e^8).
// ---------------------------------------------------------------------------
__global__ __launch_bounds__(256) void attn_kernel(
    const bh16* __restrict__ Qn, const bh16* __restrict__ Kn, const bh16* __restrict__ Vt,
    const float* __restrict__ alibi, const float* __restrict__ maskl2,
    const float* __restrict__ lscale, bh16* __restrict__ ao) {
  __shared__ bh16 plds_s[4 * 16 * 72];   // per-wave P^T [16 q][64 k], stride 72
  const int tid = threadIdx.x;
  const int wave = tid >> 6, lane = tid & 63;
  const int l15 = lane & 15, g = lane >> 4;
  // XCD swizzle: xcd = bid&7 (round-robin dispatch), 4 bh per XCD, 32 q-tiles/bh
  const int bid = blockIdx.x;
  const int slot = bid >> 3;
  const int bh = (bid & 7) * 4 + (slot & 3);
  const int qt = slot >> 2;
  const int b = bh >> 4, h = bh & 15;
  const int qw = qt * 64 + wave * 16;
  bh16* plds = plds_s + wave * (16 * 72);

  const float scale2 = __expf(fminf(lscale[h], LOGMAX)) * LOG2E;
  // Q fragment = B operand (n = q = l15), reused all iterations
  const bh16* qp = Qn + ((size_t)bh * 2048 + qw + l15) * 64 + g * 8;
  const s16x8 bq0 = *(const s16x8*)qp;
  const s16x8 bq1 = *(const s16x8*)(qp + 32);

  const bh16* Kb = Kn + (size_t)bh * 2048 * 64;
  const bh16* Vb = Vt + (size_t)bh * 64 * 2048;
  const float* alibase = alibi + ((size_t)bh * 2048 + qw + l15) * 2048;
  const float* mbase = maskl2 + b * 2048;

  f32x4 Oa[4] = {};
  float m2 = -43.0f, l_run = 0.0f;       // log2-domain running max

  // prefetch alibi (log2-scaled, mask folded as additive -1e30) for kt=0
  f32x4 al[4];
#pragma unroll
  for (int nb = 0; nb < 4; ++nb) {
    f32x4 a  = *(const f32x4*)(alibase + nb * 16 + g * 4);
    f32x4 mm = *(const f32x4*)(mbase + nb * 16 + g * 4);
#pragma unroll
    for (int r = 0; r < 4; ++r) al[nb][r] = a[r] * LOG2E + mm[r];
  }

  for (int kt = 0; kt < 32; ++kt) {
    const int k0 = kt * 64;

    // S^T = K·Q^T : A = K rows (m = key) straight from global (L1/L2 hit)
    f32x4 s[4];
#pragma unroll
    for (int nb = 0; nb < 4; ++nb) {
      const int kr = nb * 16 + l15;
      const bh16* kp = Kb + (size_t)(k0 + kr) * 64 + g * 8;
      s16x8 ak0 = *(const s16x8*)kp;
      s16x8 ak1 = *(const s16x8*)(kp + 32);
      f32x4 z = {0.f, 0.f, 0.f, 0.f};
      z = mfma_bf16(ak0, bq0, z);
      z = mfma_bf16(ak1, bq1, z);
      s[nb] = z;
    }

    // prefetch next tile's alibi/mask — a full iteration of latency cover,
    // and with no barriers in the loop nothing drains it early
    f32x4 aln[4];
    if (kt < 31) {
      const int k1 = k0 + 64;
#pragma unroll
      for (int nb = 0; nb < 4; ++nb) {
        f32x4 a  = *(const f32x4*)(alibase + k1 + nb * 16 + g * 4);
        f32x4 mm = *(const f32x4*)(mbase + k1 + nb * 16 + g * 4);
#pragma unroll
        for (int r = 0; r < 4; ++r) aln[nb][r] = a[r] * LOG2E + mm[r];
      }
    }

    // online softmax (log2 domain); per-lane q = l15, key reduce = xor16/32
    float lm = -3.0e38f;
#pragma unroll
    for (int nb = 0; nb < 4; ++nb)
#pragma unroll
      for (int r = 0; r < 4; ++r) {
        float v = s[nb][r] * scale2 + al[nb][r];
        s[nb][r] = v;
        lm = fmaxf(lm, v);
      }
    lm = fmaxf(lm, __shfl_xor(lm, 16, 64));
    lm = fmaxf(lm, __shfl_xor(lm, 32, 64));
    if (!__all(lm - m2 <= 11.5f)) {      // T13 defer-max: P bounded by 2^11.5
      float mnew = fmaxf(m2, lm);
      float alpha = __builtin_amdgcn_exp2f(m2 - mnew);
      m2 = mnew;
      l_run *= alpha;
#pragma unroll
      for (int nd = 0; nd < 4; ++nd)
#pragma unroll
        for (int r = 0; r < 4; ++r) Oa[nd][r] *= alpha;
    }
    float rs = 0.f;
#pragma unroll
    for (int nb = 0; nb < 4; ++nb)
#pragma unroll
      for (int r = 0; r < 4; ++r) {
        float p = __builtin_amdgcn_exp2f(s[nb][r] - m2);
        s[nb][r] = p;
        rs += p;
      }
    rs += __shfl_xor(rs, 16, 64);
    rs += __shfl_xor(rs, 32, 64);
    l_run += rs;

    // P^T -> plds [q][k] (wave-private: no barrier, 2-way bank alias = free)
#pragma unroll
    for (int nb = 0; nb < 4; ++nb) {
      u16x4 pk;
      pk[0] = f2bf(s[nb][0]); pk[1] = f2bf(s[nb][1]);
      pk[2] = f2bf(s[nb][2]); pk[3] = f2bf(s[nb][3]);
      *(u16x4*)(plds + l15 * 72 + nb * 16 + g * 4) = pk;
    }

    // O^T tile: A = V rows (m = d) straight from global Vt (L1/L2 hit)
    s16x8 bp0 = *(const s16x8*)(plds + l15 * 72 + g * 8);
    s16x8 bp1 = *(const s16x8*)(plds + l15 * 72 + 32 + g * 8);
#pragma unroll
    for (int nd = 0; nd < 4; ++nd) {
      const int dr = nd * 16 + l15;
      const bh16* vp = Vb + (size_t)dr * 2048 + k0 + g * 8;
      s16x8 av0 = *(const s16x8*)vp;
      s16x8 av1 = *(const s16x8*)(vp + 32);
      Oa[nd] = mfma_bf16(av0, bp0, Oa[nd]);
      Oa[nd] = mfma_bf16(av1, bp1, Oa[nd]);
    }
    if (kt < 31) {
#pragma unroll
      for (int nb = 0; nb < 4; ++nb) al[nb] = aln[nb];
    }
  }

  // epilogue: O[q=l15][d = nd*16 + g*4 + r] -> vectorized u16x4 stores
  const float inv = 1.0f / l_run;
  const size_t rowo = ((size_t)b * 2048 + qw + l15) * 1024 + h * 64;
#pragma unroll
  for (int nd = 0; nd < 4; ++nd) {
    u16x4 o;
    o[0] = f2bf(Oa[nd][0] * inv); o[1] = f2bf(Oa[nd][1] * inv);
    o[2] = f2bf(Oa[nd][2] * inv); o[3] = f2bf(Oa[nd][3] * inv);
    *(u16x4*)(ao + rowo + nd * 16 + g * 4) = o;
  }
}

// ---------------------------------------------------------------------------
// Kernel 3: proj GEMM (NT) + bias, fp32 out. M=4096, N'=1024, K=1024.
// ---------------------------------------------------------------------------
__global__ __launch_bounds__(256) void proj_kernel(
    const bh16* __restrict__ ab, const bh16* __restrict__ wpb,
    const float* __restrict__ bias, float* __restrict__ out) {
  __shared__ bh16 smem[8192];           // 16 KB staging
  bh16* As = smem;
  bh16* Bs = smem + 4096;
  const int tid = threadIdx.x;
  const int wave = tid >> 6, lane = tid & 63;
  const int l15 = lane & 15, g = lane >> 4;
  const int m0 = blockIdx.x * 128;
  const int n0 = blockIdx.y * 128;
  const int wm = (wave & 1) * 64, wn = (wave >> 1) * 64;

  f32x4 acc[4][4] = {};

  for (int k0 = 0; k0 < 1024; k0 += 32) {
#pragma unroll
    for (int r = 0; r < 2; ++r) {
      int chunk = r * 256 + tid;
      int row = chunk >> 2, ko = chunk & 3;
      async16(ab  + (size_t)(m0 + row) * 1024 + k0 + ko * 8, (void*)(As + chunk * 8));
      async16(wpb + (size_t)(n0 + row) * 1024 + k0 + ko * 8, (void*)(Bs + chunk * 8));
    }
    __syncthreads();
    s16x8 af[4], bfv[4];
#pragma unroll
    for (int i = 0; i < 4; ++i) af[i]  = *(const s16x8*)(As + (wm + i * 16 + l15) * 32 + g * 8);
#pragma unroll
    for (int i = 0; i < 4; ++i) bfv[i] = *(const s16x8*)(Bs + (wn + i * 16 + l15) * 32 + g * 8);
#pragma unroll
    for (int mi = 0; mi < 4; ++mi)
#pragma unroll
      for (int ni = 0; ni < 4; ++ni)
        acc[mi][ni] = mfma_bf16(af[mi], bfv[ni], acc[mi][ni]);
    __syncthreads();
  }

  float bi[4];
#pragma unroll
  for (int ni = 0; ni < 4; ++ni) bi[ni] = bias[n0 + wn + ni * 16 + l15];
#pragma unroll
  for (int mi = 0; mi < 4; ++mi)
#pragma unroll
    for (int r = 0; r < 4; ++r)
#pragma unroll
      for (int ni = 0; ni < 4; ++ni)
        out[(size_t)(m0 + wm + mi * 16 + g * 4 + r) * 1024 + n0 + wn + ni * 16 + l15] =
            acc[mi][ni][r] + bi[ni];
}

// ---------------------------------------------------------------------------
extern "C" void kernel_launch(void* const* d_in, const int* in_sizes, int n_in,
                              void* d_out, int out_size, void* d_ws, size_t ws_size,
                              hipStream_t stream) {
  const float* x     = (const float*)d_in[0];
  const int*   mask  = (const int*)d_in[1];    // padding_mask (bool -> int32)
  const float* alibi = (const float*)d_in[2];
  const float* qkvw  = (const float*)d_in[3];
  const float* projw = (const float*)d_in[4];
  const float* projb = (const float*)d_in[5];
  const float* lsc   = (const float*)d_in[6];

  char* ws = (char*)d_ws;                       // 48 MB used
  bh16* xb  = (bh16*)(ws);                      //  8 MB  x bf16 [4096][1024]
  bh16* wqb = (bh16*)(ws + 8388608);            //  6 MB  qkv_w bf16 [3072][1024]
  bh16* wpb = (bh16*)(ws + 14680064);           //  2 MB  proj_w bf16 [1024][1024]
  bh16* Qn  = (bh16*)(ws + 16777216);           //  8 MB  normalized Q [bh][n][d]
  bh16* Kn  = (bh16*)(ws + 25165824);           //  8 MB  normalized K [bh][n][d]
  bh16* Vt  = (bh16*)(ws + 33554432);           //  8 MB  V^T [bh][d][n]
  bh16* ao  = (bh16*)(ws + 41943040);           //  8 MB  attn out [b][n][h*64+d]

  // maskl2: 16 KB of {0,-1e30} per (b,key). Use ws tail if it exists,
  // else the tail of d_out (written by cast, read by attn, clobbered only
  // by proj afterwards — stream-ordered, safe).
  float* maskl2;
  if (ws_size >= 50331648 + 16384) maskl2 = (float*)(ws + 50331648);
  else                             maskl2 = (float*)((char*)d_out + out_size - 16384);

  cast_kernel<<<8196, 256, 0, stream>>>(x, qkvw, projw, mask, xb, wqb, wpb, maskl2);
  qkv_kernel<<<dim3(32, 24), 256, 0, stream>>>(xb, wqb, Qn, Kn, Vt);
  attn_kernel<<<1024, 256, 0, stream>>>(Qn, Kn, Vt, alibi, maskl2, lsc, ao);
  proj_kernel<<<dim3(32, 8), 256, 0, stream>>>(ao, wpb, projb, (float*)d_out);
}

// Round 2
// 858.117 us; speedup vs baseline: 1.2765x; 1.2765x over previous
//
#include <hip/hip_runtime.h>
#include <stdint.h>

// Problem constants
//   B=2, N=2048, C=1024, H=16, D=64, 3C=3072
#define LOGMAX 4.605170185988091f  // log(100)
#define LOG2E  1.44269504f

typedef __attribute__((ext_vector_type(4))) float f32x4;
typedef __attribute__((ext_vector_type(8))) short s16x8;   // 8 bf16 (4 VGPRs)
typedef __attribute__((ext_vector_type(4))) unsigned short u16x4;
typedef unsigned short bh16;

__device__ __forceinline__ bh16 f2bf(float f) {
  union { float f; uint32_t u; } c; c.f = f;
  uint32_t u = c.u;
  u += 0x7fffu + ((u >> 16) & 1u);   // round-to-nearest-even
  return (bh16)(u >> 16);
}

__device__ __forceinline__ void async16(const void* g, void* l) {
  __builtin_amdgcn_global_load_lds((const __attribute__((address_space(1))) void*)g,
                                   (__attribute__((address_space(3))) void*)l, 16, 0, 0);
}

__device__ __forceinline__ f32x4 mfma_bf16(s16x8 a, s16x8 b, f32x4 c) {
  return __builtin_amdgcn_mfma_f32_16x16x32_bf16(a, b, c, 0, 0, 0);
}

// ---------------------------------------------------------------------------
// Kernel 0: fp32 -> bf16 casts for x (4M), qkv_w (3M), proj_w (1M)
//   + mask -> log2-domain additive bias maskl2[b*2048+k] in {0, -1e30}
// ---------------------------------------------------------------------------
__global__ __launch_bounds__(256) void cast_kernel(
    const float* __restrict__ x, const float* __restrict__ wq, const float* __restrict__ wp,
    const int* __restrict__ mask,
    bh16* __restrict__ xb, bh16* __restrict__ wqb, bh16* __restrict__ wpb,
    float* __restrict__ maskl2) {
  int i = blockIdx.x * 256 + threadIdx.x;           // chunk of 4 floats
  if (i >= 2097152) {                               // mask chunks: 1024 of 4
    int j = i - 2097152;
    int4 m4 = *(const int4*)(mask + j * 4);
    f32x4 o;
    o[0] = m4.x ? -1.0e30f : 0.0f;
    o[1] = m4.y ? -1.0e30f : 0.0f;
    o[2] = m4.z ? -1.0e30f : 0.0f;
    o[3] = m4.w ? -1.0e30f : 0.0f;
    *(f32x4*)(maskl2 + j * 4) = o;
    return;
  }
  const float* s; bh16* d; int j;
  if (i < 1048576)      { s = x;  d = xb;  j = i; }
  else if (i < 1835008) { s = wq; d = wqb; j = i - 1048576; }
  else                  { s = wp; d = wpb; j = i - 1835008; }
  f32x4 v = *(const f32x4*)(s + (size_t)j * 4);
  u16x4 o;
  o[0] = f2bf(v[0]); o[1] = f2bf(v[1]); o[2] = f2bf(v[2]); o[3] = f2bf(v[3]);
  *(u16x4*)(d + (size_t)j * 4) = o;
}

// ---------------------------------------------------------------------------
// Kernel 1: QKV GEMM (NT): out3c[m][n'] = sum_k x[m][k]*W[n'][k]
//   M=4096 tokens, N'=3072, K=1024. 128x128 tile, BK=32, 256 thr (4 waves).
//   Epilogue: q,k rows L2-normalized -> Qn/Kn [bh][n][d] bf16,
//             v transposed -> Vt [bh][d][n] bf16.
// ---------------------------------------------------------------------------
__global__ __launch_bounds__(256) void qkv_kernel(
    const bh16* __restrict__ xb, const bh16* __restrict__ wqb,
    bh16* __restrict__ Qn, bh16* __restrict__ Kn, bh16* __restrict__ Vt) {
  __shared__ bh16 smem[18432];          // staging 16 KB; epilogue 36 KB (reused)
  bh16* As = smem;                      // [128][32] bf16
  bh16* Bs = smem + 4096;               // [128][32]
  const int tid = threadIdx.x;
  const int wave = tid >> 6, lane = tid & 63;
  const int l15 = lane & 15, g = lane >> 4;
  const int m0 = blockIdx.x * 128;      // token rows
  const int n0 = blockIdx.y * 128;      // 3C cols
  const int wm = (wave & 1) * 64, wn = (wave >> 1) * 64;

  f32x4 acc[4][4] = {};

  for (int k0 = 0; k0 < 1024; k0 += 32) {
#pragma unroll
    for (int r = 0; r < 2; ++r) {
      int chunk = r * 256 + tid;                // 512 chunks of 16 B per tile
      int row = chunk >> 2, ko = chunk & 3;
      async16(xb  + (size_t)(m0 + row) * 1024 + k0 + ko * 8, (void*)(As + chunk * 8));
      async16(wqb + (size_t)(n0 + row) * 1024 + k0 + ko * 8, (void*)(Bs + chunk * 8));
    }
    __syncthreads();
    s16x8 af[4], bfv[4];
#pragma unroll
    for (int i = 0; i < 4; ++i) af[i]  = *(const s16x8*)(As + (wm + i * 16 + l15) * 32 + g * 8);
#pragma unroll
    for (int i = 0; i < 4; ++i) bfv[i] = *(const s16x8*)(Bs + (wn + i * 16 + l15) * 32 + g * 8);
#pragma unroll
    for (int mi = 0; mi < 4; ++mi)
#pragma unroll
      for (int ni = 0; ni < 4; ++ni)
        acc[mi][ni] = mfma_bf16(af[mi], bfv[ni], acc[mi][ni]);
    __syncthreads();
  }

  // epilogue — wave-private LDS repack buffer [64][72] bf16
  bh16* ep = smem + wave * 4608;
  const int part = n0 >> 10;                    // 0=q 1=k 2=v
  const int h = ((n0 + wn) & 1023) >> 6;
  const int b = m0 >> 11;
  const int tok0 = (m0 & 2047) + wm;
  const int bh = b * 16 + h;

  if (part < 2) {
#pragma unroll
    for (int mi = 0; mi < 4; ++mi) {
#pragma unroll
      for (int r = 0; r < 4; ++r) {
        float ss = 0.f;
#pragma unroll
        for (int ni = 0; ni < 4; ++ni) { float v = acc[mi][ni][r]; ss += v * v; }
        ss += __shfl_xor(ss, 1, 64);
        ss += __shfl_xor(ss, 2, 64);
        ss += __shfl_xor(ss, 4, 64);
        ss += __shfl_xor(ss, 8, 64);
        float rn = rsqrtf(ss);
#pragma unroll
        for (int ni = 0; ni < 4; ++ni)
          ep[(mi * 16 + g * 4 + r) * 72 + ni * 16 + l15] = f2bf(acc[mi][ni][r] * rn);
      }
    }
    bh16* dst = (part == 0 ? Qn : Kn) + ((size_t)bh * 2048 + tok0) * 64;
#pragma unroll
    for (int j = 0; j < 8; ++j) {
      int chunk = j * 64 + lane;
      int row = chunk >> 3, cc = chunk & 7;
      *(s16x8*)(dst + chunk * 8) = *(const s16x8*)(ep + row * 72 + cc * 8);
    }
  } else {
#pragma unroll
    for (int mi = 0; mi < 4; ++mi)
#pragma unroll
      for (int r = 0; r < 4; ++r)
#pragma unroll
        for (int ni = 0; ni < 4; ++ni)
          ep[(ni * 16 + l15) * 72 + mi * 16 + g * 4 + r] = f2bf(acc[mi][ni][r]);
#pragma unroll
    for (int j = 0; j < 8; ++j) {
      int chunk = j * 64 + lane;
      int drow = chunk >> 3, cc = chunk & 7;
      *(s16x8*)(Vt + ((size_t)bh * 64 + drow) * 2048 + tok0 + cc * 8) =
          *(const s16x8*)(ep + drow * 72 + cc * 8);
    }
  }
}

// ---------------------------------------------------------------------------
// Kernel 2: flash attention, S^T formulation — LDS-staged, double-buffered,
//   ONE barrier per k-tile (T3-lite 2-phase): stage(kt+1) issued at top of
//   iteration kt, compute tile kt, then a single __syncthreads whose vmcnt(0)
//   drain waits on loads issued a full compute phase earlier.
//   K/V tiles 16B-chunk XOR-swizzled in LDS; plds [16][64] XOR-swizzled.
//   LDS = 2*8K (K) + 2*8K (V) + 8K (P) = 40960 B -> 4 blocks/CU, grid 1024
//   = exactly resident (no tail). XCD swizzle keeps K/V L2-local.
//   Softmax in log2 domain + T13 defer-max.
// ---------------------------------------------------------------------------
__global__ __launch_bounds__(256) void attn_kernel(
    const bh16* __restrict__ Qn, const bh16* __restrict__ Kn, const bh16* __restrict__ Vt,
    const float* __restrict__ alibi, const float* __restrict__ maskl2,
    const float* __restrict__ lscale, bh16* __restrict__ ao) {
  __shared__ bh16 klds[2][4096];         // [key][d], 16B chunks swizzled
  __shared__ bh16 vlds[2][4096];         // [d][key], swizzled
  __shared__ bh16 plds_s[4][1024];       // per-wave P^T [16 q][64 k], XOR-swizzled
  const int tid = threadIdx.x;
  const int wave = tid >> 6, lane = tid & 63;
  const int l15 = lane & 15, g = lane >> 4;
  const int l7 = l15 & 7;
  // XCD swizzle: xcd = bid&7 (round-robin dispatch), 4 bh per XCD, 32 q-tiles/bh
  const int bid = blockIdx.x;
  const int slot = bid >> 3;
  const int bh = (bid & 7) * 4 + (slot & 3);
  const int qt = slot >> 2;
  const int b = bh >> 4, h = bh & 15;
  const int qw = qt * 64 + wave * 16;
  bh16* plds = plds_s[wave];

  const float scale2 = __expf(fminf(lscale[h], LOGMAX)) * LOG2E;
  // Q fragment = B operand (n = q = l15), reused all iterations
  const bh16* qp = Qn + ((size_t)bh * 2048 + qw + l15) * 64 + g * 8;
  const s16x8 bq0 = *(const s16x8*)qp;
  const s16x8 bq1 = *(const s16x8*)(qp + 32);

  const bh16* Kb = Kn + (size_t)bh * 2048 * 64;
  const bh16* Vb = Vt + (size_t)bh * 64 * 2048;
  const float* alibase = alibi + ((size_t)bh * 2048 + qw + l15) * 2048;
  const float* mbase = maskl2 + b * 2048;

  // staging geometry: 512 chunks of 16B per tile; chunk c -> row c>>3,
  // slot c&7 holds global 16B-chunk u = (c&7) ^ (row&7)
  const int c0 = tid;
  const int c1 = 256 + tid;
  const int r0_ = c0 >> 3, u0 = (c0 & 7) ^ (r0_ & 7);
  const int r1_ = c1 >> 3, u1 = (c1 & 7) ^ (r1_ & 7);

  f32x4 Oa[4] = {};
  float m2 = -43.0f, l_run = 0.0f;       // log2-domain running max

  // prologue: stage tile 0 into buffer 0
  async16(Kb + (size_t)r0_ * 64 + u0 * 8, (void*)(klds[0] + c0 * 8));
  async16(Kb + (size_t)r1_ * 64 + u1 * 8, (void*)(klds[0] + c1 * 8));
  async16(Vb + (size_t)r0_ * 2048 + u0 * 8, (void*)(vlds[0] + c0 * 8));
  async16(Vb + (size_t)r1_ * 2048 + u1 * 8, (void*)(vlds[0] + c1 * 8));

  // prefetch alibi (log2-scaled, mask folded as additive -1e30) for kt=0
  f32x4 al[4];
#pragma unroll
  for (int nb = 0; nb < 4; ++nb) {
    f32x4 a  = *(const f32x4*)(alibase + nb * 16 + g * 4);
    f32x4 mm = *(const f32x4*)(mbase + nb * 16 + g * 4);
#pragma unroll
    for (int r = 0; r < 4; ++r) al[nb][r] = a[r] * LOG2E + mm[r];
  }
  __syncthreads();                       // tile 0 landed

  for (int kt = 0; kt < 32; ++kt) {
    const int cur = kt & 1;
    const bh16* kl = klds[cur];
    const bh16* vl = vlds[cur];

    // issue stage of tile kt+1 into the other buffer (full-phase latency cover)
    if (kt < 31) {
      const int k1 = (kt + 1) * 64;
      async16(Kb + (size_t)(k1 + r0_) * 64 + u0 * 8, (void*)(klds[cur ^ 1] + c0 * 8));
      async16(Kb + (size_t)(k1 + r1_) * 64 + u1 * 8, (void*)(klds[cur ^ 1] + c1 * 8));
      async16(Vb + (size_t)r0_ * 2048 + k1 + u0 * 8, (void*)(vlds[cur ^ 1] + c0 * 8));
      async16(Vb + (size_t)r1_ * 2048 + k1 + u1 * 8, (void*)(vlds[cur ^ 1] + c1 * 8));
    }

    // S^T = K·Q^T : A = K rows (m = key), B = Q rows (n = q)
    f32x4 s[4];
#pragma unroll
    for (int nb = 0; nb < 4; ++nb) {
      const int kr = nb * 16 + l15;
      s16x8 ak0 = *(const s16x8*)(kl + kr * 64 + ((g ^ (kr & 7)) * 8));
      s16x8 ak1 = *(const s16x8*)(kl + kr * 64 + (((g + 4) ^ (kr & 7)) * 8));
      f32x4 z = {0.f, 0.f, 0.f, 0.f};
      z = mfma_bf16(ak0, bq0, z);
      z = mfma_bf16(ak1, bq1, z);
      s[nb] = z;
    }

    // prefetch next tile's alibi/mask (drained at end-of-iteration barrier,
    // issued a softmax+PV phase ahead of that)
    f32x4 aln[4];
    if (kt < 31) {
      const int k1 = (kt + 1) * 64;
#pragma unroll
      for (int nb = 0; nb < 4; ++nb) {
        f32x4 a  = *(const f32x4*)(alibase + k1 + nb * 16 + g * 4);
        f32x4 mm = *(const f32x4*)(mbase + k1 + nb * 16 + g * 4);
#pragma unroll
        for (int r = 0; r < 4; ++r) aln[nb][r] = a[r] * LOG2E + mm[r];
      }
    }

    // online softmax (log2 domain); per-lane q = l15, key reduce = xor16/32
    float lm = -3.0e38f;
#pragma unroll
    for (int nb = 0; nb < 4; ++nb)
#pragma unroll
      for (int r = 0; r < 4; ++r) {
        float v = s[nb][r] * scale2 + al[nb][r];
        s[nb][r] = v;
        lm = fmaxf(lm, v);
      }
    lm = fmaxf(lm, __shfl_xor(lm, 16, 64));
    lm = fmaxf(lm, __shfl_xor(lm, 32, 64));
    if (!__all(lm - m2 <= 11.5f)) {      // T13 defer-max: P bounded by 2^11.5
      float mnew = fmaxf(m2, lm);
      float alpha = __builtin_amdgcn_exp2f(m2 - mnew);
      m2 = mnew;
      l_run *= alpha;
#pragma unroll
      for (int nd = 0; nd < 4; ++nd)
#pragma unroll
        for (int r = 0; r < 4; ++r) Oa[nd][r] *= alpha;
    }
    float rs = 0.f;
#pragma unroll
    for (int nb = 0; nb < 4; ++nb)
#pragma unroll
      for (int r = 0; r < 4; ++r) {
        float p = __builtin_amdgcn_exp2f(s[nb][r] - m2);
        s[nb][r] = p;
        rs += p;
      }
    rs += __shfl_xor(rs, 16, 64);
    rs += __shfl_xor(rs, 32, 64);
    l_run += rs;

    // P^T -> plds [q=l15][k], 16B-slot XOR swizzle (2-way = free)
#pragma unroll
    for (int nb = 0; nb < 4; ++nb) {
      u16x4 pk;
      pk[0] = f2bf(s[nb][0]); pk[1] = f2bf(s[nb][1]);
      pk[2] = f2bf(s[nb][2]); pk[3] = f2bf(s[nb][3]);
      const int ps = nb * 2 + (g >> 1);                  // 16B slot 0..7
      *(u16x4*)(plds + l15 * 64 + ((ps ^ l7) << 3) + (g & 1) * 4) = pk;
    }

    // O^T tile: A = V rows (m = d) from vlds, B = P rows (n = q) from plds
    s16x8 bp0 = *(const s16x8*)(plds + l15 * 64 + ((g ^ l7) << 3));
    s16x8 bp1 = *(const s16x8*)(plds + l15 * 64 + (((4 + g) ^ l7) << 3));
#pragma unroll
    for (int nd = 0; nd < 4; ++nd) {
      const int dr = nd * 16 + l15;
      s16x8 av0 = *(const s16x8*)(vl + dr * 64 + ((g ^ (dr & 7)) * 8));
      s16x8 av1 = *(const s16x8*)(vl + dr * 64 + (((g + 4) ^ (dr & 7)) * 8));
      Oa[nd] = mfma_bf16(av0, bp0, Oa[nd]);
      Oa[nd] = mfma_bf16(av1, bp1, Oa[nd]);
    }

    if (kt < 31) {
      __syncthreads();   // single drain: stage(kt+1) + alibi(kt+1) complete
#pragma unroll
      for (int nb = 0; nb < 4; ++nb) al[nb] = aln[nb];
    }
  }

  // epilogue: O[q=l15][d = nd*16 + g*4 + r] -> vectorized u16x4 stores
  const float inv = 1.0f / l_run;
  const size_t rowo = ((size_t)b * 2048 + qw + l15) * 1024 + h * 64;
#pragma unroll
  for (int nd = 0; nd < 4; ++nd) {
    u16x4 o;
    o[0] = f2bf(Oa[nd][0] * inv); o[1] = f2bf(Oa[nd][1] * inv);
    o[2] = f2bf(Oa[nd][2] * inv); o[3] = f2bf(Oa[nd][3] * inv);
    *(u16x4*)(ao + rowo + nd * 16 + g * 4) = o;
  }
}

// ---------------------------------------------------------------------------
// Kernel 3: proj GEMM (NT) + bias, fp32 out. M=4096, N'=1024, K=1024.
// ---------------------------------------------------------------------------
__global__ __launch_bounds__(256) void proj_kernel(
    const bh16* __restrict__ ab, const bh16* __restrict__ wpb,
    const float* __restrict__ bias, float* __restrict__ out) {
  __shared__ bh16 smem[8192];           // 16 KB staging
  bh16* As = smem;
  bh16* Bs = smem + 4096;
  const int tid = threadIdx.x;
  const int wave = tid >> 6, lane = tid & 63;
  const int l15 = lane & 15, g = lane >> 4;
  const int m0 = blockIdx.x * 128;
  const int n0 = blockIdx.y * 128;
  const int wm = (wave & 1) * 64, wn = (wave >> 1) * 64;

  f32x4 acc[4][4] = {};

  for (int k0 = 0; k0 < 1024; k0 += 32) {
#pragma unroll
    for (int r = 0; r < 2; ++r) {
      int chunk = r * 256 + tid;
      int row = chunk >> 2, ko = chunk & 3;
      async16(ab  + (size_t)(m0 + row) * 1024 + k0 + ko * 8, (void*)(As + chunk * 8));
      async16(wpb + (size_t)(n0 + row) * 1024 + k0 + ko * 8, (void*)(Bs + chunk * 8));
    }
    __syncthreads();
    s16x8 af[4], bfv[4];
#pragma unroll
    for (int i = 0; i < 4; ++i) af[i]  = *(const s16x8*)(As + (wm + i * 16 + l15) * 32 + g * 8);
#pragma unroll
    for (int i = 0; i < 4; ++i) bfv[i] = *(const s16x8*)(Bs + (wn + i * 16 + l15) * 32 + g * 8);
#pragma unroll
    for (int mi = 0; mi < 4; ++mi)
#pragma unroll
      for (int ni = 0; ni < 4; ++ni)
        acc[mi][ni] = mfma_bf16(af[mi], bfv[ni], acc[mi][ni]);
    __syncthreads();
  }

  float bi[4];
#pragma unroll
  for (int ni = 0; ni < 4; ++ni) bi[ni] = bias[n0 + wn + ni * 16 + l15];
#pragma unroll
  for (int mi = 0; mi < 4; ++mi)
#pragma unroll
    for (int r = 0; r < 4; ++r)
#pragma unroll
      for (int ni = 0; ni < 4; ++ni)
        out[(size_t)(m0 + wm + mi * 16 + g * 4 + r) * 1024 + n0 + wn + ni * 16 + l15] =
            acc[mi][ni][r] + bi[ni];
}

// ---------------------------------------------------------------------------
extern "C" void kernel_launch(void* const* d_in, const int* in_sizes, int n_in,
                              void* d_out, int out_size, void* d_ws, size_t ws_size,
                              hipStream_t stream) {
  const float* x     = (const float*)d_in[0];
  const int*   mask  = (const int*)d_in[1];    // padding_mask (bool -> int32)
  const float* alibi = (const float*)d_in[2];
  const float* qkvw  = (const float*)d_in[3];
  const float* projw = (const float*)d_in[4];
  const float* projb = (const float*)d_in[5];
  const float* lsc   = (const float*)d_in[6];

  char* ws = (char*)d_ws;                       // 48 MB used
  bh16* xb  = (bh16*)(ws);                      //  8 MB  x bf16 [4096][1024]
  bh16* wqb = (bh16*)(ws + 8388608);            //  6 MB  qkv_w bf16 [3072][1024]
  bh16* wpb = (bh16*)(ws + 14680064);           //  2 MB  proj_w bf16 [1024][1024]
  bh16* Qn  = (bh16*)(ws + 16777216);           //  8 MB  normalized Q [bh][n][d]
  bh16* Kn  = (bh16*)(ws + 25165824);           //  8 MB  normalized K [bh][n][d]
  bh16* Vt  = (bh16*)(ws + 33554432);           //  8 MB  V^T [bh][d][n]
  bh16* ao  = (bh16*)(ws + 41943040);           //  8 MB  attn out [b][n][h*64+d]

  // maskl2: 16 KB of {0,-1e30} per (b,key). Use ws tail if it exists,
  // else the tail of d_out (written by cast, read by attn, clobbered only
  // by proj afterwards — stream-ordered, safe).
  float* maskl2;
  if (ws_size >= 50331648 + 16384) maskl2 = (float*)(ws + 50331648);
  else                             maskl2 = (float*)((char*)d_out + out_size - 16384);

  cast_kernel<<<8196, 256, 0, stream>>>(x, qkvw, projw, mask, xb, wqb, wpb, maskl2);
  qkv_kernel<<<dim3(32, 24), 256, 0, stream>>>(xb, wqb, Qn, Kn, Vt);
  attn_kernel<<<1024, 256, 0, stream>>>(Qn, Kn, Vt, alibi, maskl2, lsc, ao);
  proj_kernel<<<dim3(32, 8), 256, 0, stream>>>(ao, wpb, projb, (float*)d_out);
}

// Round 3
// 856.200 us; speedup vs baseline: 1.2793x; 1.0022x over previous
//
#include <hip/hip_runtime.h>
#include <stdint.h>

// Problem constants
//   B=2, N=2048, C=1024, H=16, D=64, 3C=3072
#define LOGMAX 4.605170185988091f  // log(100)
#define LOG2E  1.44269504f

typedef __attribute__((ext_vector_type(4))) float f32x4;
typedef __attribute__((ext_vector_type(8))) short s16x8;   // 8 bf16 (4 VGPRs)
typedef __attribute__((ext_vector_type(4))) unsigned short u16x4;
typedef unsigned short bh16;

__device__ __forceinline__ bh16 f2bf(float f) {
  union { float f; uint32_t u; } c; c.f = f;
  uint32_t u = c.u;
  u += 0x7fffu + ((u >> 16) & 1u);   // round-to-nearest-even
  return (bh16)(u >> 16);
}

__device__ __forceinline__ void async16(const void* g, void* l) {
  __builtin_amdgcn_global_load_lds((const __attribute__((address_space(1))) void*)g,
                                   (__attribute__((address_space(3))) void*)l, 16, 0, 0);
}

__device__ __forceinline__ f32x4 mfma_bf16(s16x8 a, s16x8 b, f32x4 c) {
  return __builtin_amdgcn_mfma_f32_16x16x32_bf16(a, b, c, 0, 0, 0);
}

// ---------------------------------------------------------------------------
// Kernel 0: fp32 -> bf16 casts for x (4M), qkv_w (3M), proj_w (1M)
//   + mask -> bit-words mbits[b*64 + w] (bit j = key w*32+j padded)
// ---------------------------------------------------------------------------
__global__ __launch_bounds__(256) void cast_kernel(
    const float* __restrict__ x, const float* __restrict__ wq, const float* __restrict__ wp,
    const int* __restrict__ mask,
    bh16* __restrict__ xb, bh16* __restrict__ wqb, bh16* __restrict__ wpb,
    uint32_t* __restrict__ mbits) {
  if (blockIdx.x == 8192) {                          // mask bit-pack: 128 words
    int t = threadIdx.x;
    if (t < 128) {
      int b = t >> 6, w = t & 63;
      uint32_t word = 0;
      for (int j = 0; j < 32; ++j)
        word |= (mask[b * 2048 + w * 32 + j] ? 1u : 0u) << j;
      mbits[b * 64 + w] = word;
    }
    return;
  }
  int i = blockIdx.x * 256 + threadIdx.x;           // chunk of 4 floats
  const float* s; bh16* d; int j;
  if (i < 1048576)      { s = x;  d = xb;  j = i; }
  else if (i < 1835008) { s = wq; d = wqb; j = i - 1048576; }
  else                  { s = wp; d = wpb; j = i - 1835008; }
  f32x4 v = *(const f32x4*)(s + (size_t)j * 4);
  u16x4 o;
  o[0] = f2bf(v[0]); o[1] = f2bf(v[1]); o[2] = f2bf(v[2]); o[3] = f2bf(v[3]);
  *(u16x4*)(d + (size_t)j * 4) = o;
}

// ---------------------------------------------------------------------------
// GEMM staging helper: 128x32 bf16 tile = 512 chunks of 16B.
//   chunk c -> row c>>2; LDS slot (c&3) holds global chunk u = (c&3)^((c>>3)&3)
//   (XOR swizzle so fragment ds_read_b128 is 2-way bank-aliased = free).
//   LDS dest is lane-linear per wave (global_load_lds constraint, m104).
// ---------------------------------------------------------------------------
#define GEMM_STAGE(SRC_A, SRC_B, K0, AD, BD)                                          \
  {                                                                                   \
    async16(SRC_A + (size_t)(m0 + rS0) * 1024 + (K0) + uS0 * 8, (void*)((AD) + cS0 * 8)); \
    async16(SRC_A + (size_t)(m0 + rS1) * 1024 + (K0) + uS1 * 8, (void*)((AD) + cS1 * 8)); \
    async16(SRC_B + (size_t)(n0 + rS0) * 1024 + (K0) + uS0 * 8, (void*)((BD) + cS0 * 8)); \
    async16(SRC_B + (size_t)(n0 + rS1) * 1024 + (K0) + uS1 * 8, (void*)((BD) + cS1 * 8)); \
  }

// ---------------------------------------------------------------------------
// Kernel 1: QKV GEMM (NT), 2-phase double-buffered BK=32, 1 barrier/step.
//   M=4096 tokens, N'=3072, K=1024. 128x128 tile, 256 thr (4 waves).
//   Grid 768 1-D, XCD-swizzled (each XCD owns 3 consecutive B-panels).
//   Epilogue: q,k rows L2-normalized -> Qn/Kn; v transposed -> Vt.
// ---------------------------------------------------------------------------
__global__ __launch_bounds__(256) void qkv_kernel(
    const bh16* __restrict__ xb, const bh16* __restrict__ wqb,
    bh16* __restrict__ Qn, bh16* __restrict__ Kn, bh16* __restrict__ Vt) {
  __shared__ bh16 smem[18432];          // dbuf staging 32 KB; epilogue 36 KB
  bh16* As0 = smem;                     // [128][32]
  bh16* Bs0 = smem + 4096;
  bh16* As1 = smem + 8192;
  bh16* Bs1 = smem + 12288;
  const int tid = threadIdx.x;
  const int wave = tid >> 6, lane = tid & 63;
  const int l15 = lane & 15, g = lane >> 4;
  const int q2 = (l15 >> 1) & 3;        // read-side swizzle key
  // XCD swizzle: 768 blocks, 96 per XCD = 3 full n-panel columns
  const int bid = blockIdx.x;
  const int swz = (bid & 7) * 96 + (bid >> 3);
  const int m0 = (swz & 31) * 128;      // token rows
  const int n0 = (swz >> 5) * 128;      // 3C cols
  const int wm = (wave & 1) * 64, wn = (wave >> 1) * 64;

  // stage geometry (2 chunks each of A and B per thread)
  const int cS0 = tid, cS1 = tid + 256;
  const int rS0 = cS0 >> 2, uS0 = (cS0 & 3) ^ ((cS0 >> 3) & 3);
  const int rS1 = cS1 >> 2, uS1 = (cS1 & 3) ^ ((cS1 >> 3) & 3);

  f32x4 acc[4][4] = {};

  GEMM_STAGE(xb, wqb, 0, As0, Bs0);
  __syncthreads();

  for (int t = 0; t < 32; ++t) {
    const bh16* Ar = (t & 1) ? As1 : As0;
    const bh16* Br = (t & 1) ? Bs1 : Bs0;
    bh16* Aw = (t & 1) ? As0 : As1;
    bh16* Bw = (t & 1) ? Bs0 : Bs1;
    if (t < 31) GEMM_STAGE(xb, wqb, (t + 1) * 32, Aw, Bw);
    s16x8 af[4], bfv[4];
#pragma unroll
    for (int i = 0; i < 4; ++i)
      af[i] = *(const s16x8*)(Ar + (wm + i * 16 + l15) * 32 + ((g ^ q2) * 8));
#pragma unroll
    for (int i = 0; i < 4; ++i)
      bfv[i] = *(const s16x8*)(Br + (wn + i * 16 + l15) * 32 + ((g ^ q2) * 8));
#pragma unroll
    for (int mi = 0; mi < 4; ++mi)
#pragma unroll
      for (int ni = 0; ni < 4; ++ni)
        acc[mi][ni] = mfma_bf16(af[mi], bfv[ni], acc[mi][ni]);
    __syncthreads();
  }

  // epilogue — wave-private LDS repack buffer [64][72] bf16
  bh16* ep = smem + wave * 4608;
  const int part = n0 >> 10;                    // 0=q 1=k 2=v
  const int h = ((n0 + wn) & 1023) >> 6;
  const int b = m0 >> 11;
  const int tok0 = (m0 & 2047) + wm;
  const int bh = b * 16 + h;

  if (part < 2) {
#pragma unroll
    for (int mi = 0; mi < 4; ++mi) {
#pragma unroll
      for (int r = 0; r < 4; ++r) {
        float ss = 0.f;
#pragma unroll
        for (int ni = 0; ni < 4; ++ni) { float v = acc[mi][ni][r]; ss += v * v; }
        ss += __shfl_xor(ss, 1, 64);
        ss += __shfl_xor(ss, 2, 64);
        ss += __shfl_xor(ss, 4, 64);
        ss += __shfl_xor(ss, 8, 64);
        float rn = rsqrtf(ss);
#pragma unroll
        for (int ni = 0; ni < 4; ++ni)
          ep[(mi * 16 + g * 4 + r) * 72 + ni * 16 + l15] = f2bf(acc[mi][ni][r] * rn);
      }
    }
    bh16* dst = (part == 0 ? Qn : Kn) + ((size_t)bh * 2048 + tok0) * 64;
#pragma unroll
    for (int j = 0; j < 8; ++j) {
      int chunk = j * 64 + lane;
      int row = chunk >> 3, cc = chunk & 7;
      *(s16x8*)(dst + chunk * 8) = *(const s16x8*)(ep + row * 72 + cc * 8);
    }
  } else {
#pragma unroll
    for (int mi = 0; mi < 4; ++mi)
#pragma unroll
      for (int r = 0; r < 4; ++r)
#pragma unroll
        for (int ni = 0; ni < 4; ++ni)
          ep[(ni * 16 + l15) * 72 + mi * 16 + g * 4 + r] = f2bf(acc[mi][ni][r]);
#pragma unroll
    for (int j = 0; j < 8; ++j) {
      int chunk = j * 64 + lane;
      int drow = chunk >> 3, cc = chunk & 7;
      *(s16x8*)(Vt + ((size_t)bh * 64 + drow) * 2048 + tok0 + cc * 8) =
          *(const s16x8*)(ep + drow * 72 + cc * 8);
    }
  }
}

// ---------------------------------------------------------------------------
// Kernel 2: flash attention, S^T formulation.
//   Counted-vmcnt barrier (T4): per body, stage(k+1) [4 async16] issued FIRST,
//   alibi(k+2) reload [4 f32x4] issued LATER; end-of-body barrier waits
//   vmcnt(4) -> stage retired, alibi stays in flight across the barrier
//   (~1.3 bodies of HBM latency cover). Mask read as uniform bit-words
//   (scalar loads, no vmcnt perturbation). Unroll-2 bodies give static
//   buffer/reg names (rule #20). Softmax log2-domain + T13 defer-max.
// ---------------------------------------------------------------------------
#define ATTN_BARRIER(N)                                          \
  {                                                              \
    __builtin_amdgcn_sched_barrier(0);                           \
    asm volatile("s_waitcnt vmcnt(" #N ")" ::: "memory");        \
    __builtin_amdgcn_s_barrier();                                \
    __builtin_amdgcn_sched_barrier(0);                           \
  }

#define ATTN_BODY(K, KL, VL, KLN, VLN, AR, DO_STAGE, DO_RELOAD)                    \
  {                                                                                \
    const int k0_ = (K) * 64;                                                      \
    if (DO_STAGE) {                                                                \
      const int k1_ = k0_ + 64;                                                    \
      async16(Kb + (size_t)(k1_ + r0_) * 64 + u0 * 8, (void*)((KLN) + c0 * 8));    \
      async16(Kb + (size_t)(k1_ + r1_) * 64 + u1 * 8, (void*)((KLN) + c1 * 8));    \
      async16(Vb + (size_t)r0_ * 2048 + k1_ + u0 * 8, (void*)((VLN) + c0 * 8));    \
      async16(Vb + (size_t)r1_ * 2048 + k1_ + u1 * 8, (void*)((VLN) + c1 * 8));    \
      __builtin_amdgcn_sched_barrier(0); /* pin: nothing hoists above stage */     \
    }                                                                              \
    f32x4 s[4];                                                                    \
    _Pragma("unroll")                                                              \
    for (int nb = 0; nb < 4; ++nb) {                                               \
      const int kr = nb * 16 + l15;                                                \
      s16x8 ak0 = *(const s16x8*)((KL) + kr * 64 + ((g ^ (kr & 7)) * 8));          \
      s16x8 ak1 = *(const s16x8*)((KL) + kr * 64 + (((g + 4) ^ (kr & 7)) * 8));    \
      f32x4 z = {0.f, 0.f, 0.f, 0.f};                                              \
      z = mfma_bf16(ak0, bq0, z);                                                  \
      z = mfma_bf16(ak1, bq1, z);                                                  \
      s[nb] = z;                                                                   \
    }                                                                              \
    const uint32_t w0_ = mb[(K) * 2], w1_ = mb[(K) * 2 + 1];                       \
    float lm = -3.0e38f;                                                           \
    _Pragma("unroll")                                                              \
    for (int nb = 0; nb < 4; ++nb) {                                               \
      const uint32_t ww_ = (nb < 2) ? w0_ : w1_;                                   \
      _Pragma("unroll")                                                            \
      for (int r = 0; r < 4; ++r) {                                                \
        float v = s[nb][r] * scale2 + AR[nb][r] * LOG2E;                           \
        if ((ww_ >> ((nb & 1) * 16 + g * 4 + r)) & 1u) v = -1.0e30f;               \
        s[nb][r] = v;                                                              \
        lm = fmaxf(lm, v);                                                         \
      }                                                                            \
    }                                                                              \
    lm = fmaxf(lm, __shfl_xor(lm, 16, 64));                                        \
    lm = fmaxf(lm, __shfl_xor(lm, 32, 64));                                        \
    if (DO_RELOAD) {                                                               \
      const float* ab2_ = alibase + ((K) + 2) * 64;                                \
      _Pragma("unroll")                                                            \
      for (int nb = 0; nb < 4; ++nb)                                               \
        AR[nb] = *(const f32x4*)(ab2_ + nb * 16 + g * 4);                          \
    }                                                                              \
    if (!__all(lm - m2 <= 11.5f)) {                                                \
      float mnew = fmaxf(m2, lm);                                                  \
      float alpha = __builtin_amdgcn_exp2f(m2 - mnew);                             \
      m2 = mnew; l_run *= alpha;                                                   \
      _Pragma("unroll")                                                            \
      for (int nd = 0; nd < 4; ++nd)                                               \
        _Pragma("unroll")                                                          \
        for (int r = 0; r < 4; ++r) Oa[nd][r] *= alpha;                            \
    }                                                                              \
    float rs = 0.f;                                                                \
    _Pragma("unroll")                                                              \
    for (int nb = 0; nb < 4; ++nb)                                                 \
      _Pragma("unroll")                                                            \
      for (int r = 0; r < 4; ++r) {                                                \
        float p = __builtin_amdgcn_exp2f(s[nb][r] - m2);                           \
        s[nb][r] = p;                                                              \
        rs += p;                                                                   \
      }                                                                            \
    rs += __shfl_xor(rs, 16, 64);                                                  \
    rs += __shfl_xor(rs, 32, 64);                                                  \
    l_run += rs;                                                                   \
    _Pragma("unroll")                                                              \
    for (int nb = 0; nb < 4; ++nb) {                                               \
      u16x4 pk;                                                                    \
      pk[0] = f2bf(s[nb][0]); pk[1] = f2bf(s[nb][1]);                              \
      pk[2] = f2bf(s[nb][2]); pk[3] = f2bf(s[nb][3]);                              \
      const int ps_ = nb * 2 + (g >> 1);                                           \
      *(u16x4*)(plds + l15 * 64 + ((ps_ ^ l7) << 3) + (g & 1) * 4) = pk;           \
    }                                                                              \
    s16x8 bp0 = *(const s16x8*)(plds + l15 * 64 + ((g ^ l7) << 3));                \
    s16x8 bp1 = *(const s16x8*)(plds + l15 * 64 + (((4 + g) ^ l7) << 3));          \
    _Pragma("unroll")                                                              \
    for (int nd = 0; nd < 4; ++nd) {                                               \
      const int dr = nd * 16 + l15;                                                \
      s16x8 av0 = *(const s16x8*)((VL) + dr * 64 + ((g ^ (dr & 7)) * 8));          \
      s16x8 av1 = *(const s16x8*)((VL) + dr * 64 + (((g + 4) ^ (dr & 7)) * 8));    \
      Oa[nd] = mfma_bf16(av0, bp0, Oa[nd]);                                        \
      Oa[nd] = mfma_bf16(av1, bp1, Oa[nd]);                                        \
    }                                                                              \
  }

__global__ __launch_bounds__(256) void attn_kernel(
    const bh16* __restrict__ Qn, const bh16* __restrict__ Kn, const bh16* __restrict__ Vt,
    const float* __restrict__ alibi, const uint32_t* __restrict__ mbits,
    const float* __restrict__ lscale, bh16* __restrict__ ao) {
  __shared__ bh16 klds[2][4096];         // [key][d], 16B chunks swizzled
  __shared__ bh16 vlds[2][4096];         // [d][key], swizzled
  __shared__ bh16 plds_s[4][1024];       // per-wave P^T [16 q][64 k], XOR-swizzled
  const int tid = threadIdx.x;
  const int wave = tid >> 6, lane = tid & 63;
  const int l15 = lane & 15, g = lane >> 4;
  const int l7 = l15 & 7;
  // XCD swizzle: 4 bh per XCD (K/V 2 MB L2-resident), 32 q-tiles/bh
  const int bid = blockIdx.x;
  const int slot = bid >> 3;
  const int bh = (bid & 7) * 4 + (slot & 3);
  const int qt = slot >> 2;
  const int b = bh >> 4, h = bh & 15;
  const int qw = qt * 64 + wave * 16;
  bh16* plds = plds_s[wave];

  const float scale2 = __expf(fminf(lscale[h], LOGMAX)) * LOG2E;
  const bh16* qp = Qn + ((size_t)bh * 2048 + qw + l15) * 64 + g * 8;
  const s16x8 bq0 = *(const s16x8*)qp;
  const s16x8 bq1 = *(const s16x8*)(qp + 32);

  const bh16* Kb = Kn + (size_t)bh * 2048 * 64;
  const bh16* Vb = Vt + (size_t)bh * 64 * 2048;
  const float* alibase = alibi + ((size_t)bh * 2048 + qw + l15) * 2048;
  const uint32_t* mb = mbits + b * 64;   // uniform -> scalar loads

  const int c0 = tid, c1 = 256 + tid;
  const int r0_ = c0 >> 3, u0 = (c0 & 7) ^ (r0_ & 7);
  const int r1_ = c1 >> 3, u1 = (c1 & 7) ^ (r1_ & 7);

  f32x4 Oa[4] = {};
  float m2 = -43.0f, l_run = 0.0f;       // log2-domain running max

  // prologue: stage tile 0 -> buf0; alibi tiles 0,1 -> aA/aB
  async16(Kb + (size_t)r0_ * 64 + u0 * 8, (void*)(klds[0] + c0 * 8));
  async16(Kb + (size_t)r1_ * 64 + u1 * 8, (void*)(klds[0] + c1 * 8));
  async16(Vb + (size_t)r0_ * 2048 + u0 * 8, (void*)(vlds[0] + c0 * 8));
  async16(Vb + (size_t)r1_ * 2048 + u1 * 8, (void*)(vlds[0] + c1 * 8));
  f32x4 aA[4], aB[4];
#pragma unroll
  for (int nb = 0; nb < 4; ++nb) {
    aA[nb] = *(const f32x4*)(alibase + nb * 16 + g * 4);
    aB[nb] = *(const f32x4*)(alibase + 64 + nb * 16 + g * 4);
  }
  __syncthreads();                       // full drain (one-time)

  // bodies 0..29 in unroll-2 pairs: stage next, reload alibi(+2), vmcnt(4)
  for (int it = 0; it < 15; ++it) {
    const int k = it * 2;
    ATTN_BODY(k,     klds[0], vlds[0], klds[1], vlds[1], aA, 1, 1);
    ATTN_BARRIER(4);
    ATTN_BODY(k + 1, klds[1], vlds[1], klds[0], vlds[0], aB, 1, 1);
    ATTN_BARRIER(4);
  }
  // body 30: stage 31, no reload, full drain at barrier
  ATTN_BODY(30, klds[0], vlds[0], klds[1], vlds[1], aA, 1, 0);
  ATTN_BARRIER(0);
  // body 31: compute only
  ATTN_BODY(31, klds[1], vlds[1], klds[0], vlds[0], aB, 0, 0);

  // epilogue: O[q=l15][d = nd*16 + g*4 + r] -> vectorized u16x4 stores
  const float inv = 1.0f / l_run;
  const size_t rowo = ((size_t)b * 2048 + qw + l15) * 1024 + h * 64;
#pragma unroll
  for (int nd = 0; nd < 4; ++nd) {
    u16x4 o;
    o[0] = f2bf(Oa[nd][0] * inv); o[1] = f2bf(Oa[nd][1] * inv);
    o[2] = f2bf(Oa[nd][2] * inv); o[3] = f2bf(Oa[nd][3] * inv);
    *(u16x4*)(ao + rowo + nd * 16 + g * 4) = o;
  }
}

// ---------------------------------------------------------------------------
// Kernel 3: proj GEMM (NT) + bias, 2-phase dbuf BK=32, XCD-swizzled grid.
//   M=4096, N'=1024, K=1024.
// ---------------------------------------------------------------------------
__global__ __launch_bounds__(256) void proj_kernel(
    const bh16* __restrict__ ab, const bh16* __restrict__ wpb,
    const float* __restrict__ bias, float* __restrict__ out) {
  __shared__ bh16 smem[16384];          // dbuf staging 32 KB
  bh16* As0 = smem;
  bh16* Bs0 = smem + 4096;
  bh16* As1 = smem + 8192;
  bh16* Bs1 = smem + 12288;
  const int tid = threadIdx.x;
  const int wave = tid >> 6, lane = tid & 63;
  const int l15 = lane & 15, g = lane >> 4;
  const int q2 = (l15 >> 1) & 3;
  const int bid = blockIdx.x;           // 256 blocks, 32 per XCD = 1 n-panel
  const int swz = (bid & 7) * 32 + (bid >> 3);
  const int m0 = (swz & 31) * 128;
  const int n0 = (swz >> 5) * 128;
  const int wm = (wave & 1) * 64, wn = (wave >> 1) * 64;

  const int cS0 = tid, cS1 = tid + 256;
  const int rS0 = cS0 >> 2, uS0 = (cS0 & 3) ^ ((cS0 >> 3) & 3);
  const int rS1 = cS1 >> 2, uS1 = (cS1 & 3) ^ ((cS1 >> 3) & 3);

  f32x4 acc[4][4] = {};

  GEMM_STAGE(ab, wpb, 0, As0, Bs0);
  __syncthreads();

  for (int t = 0; t < 32; ++t) {
    const bh16* Ar = (t & 1) ? As1 : As0;
    const bh16* Br = (t & 1) ? Bs1 : Bs0;
    bh16* Aw = (t & 1) ? As0 : As1;
    bh16* Bw = (t & 1) ? Bs0 : Bs1;
    if (t < 31) GEMM_STAGE(ab, wpb, (t + 1) * 32, Aw, Bw);
    s16x8 af[4], bfv[4];
#pragma unroll
    for (int i = 0; i < 4; ++i)
      af[i] = *(const s16x8*)(Ar + (wm + i * 16 + l15) * 32 + ((g ^ q2) * 8));
#pragma unroll
    for (int i = 0; i < 4; ++i)
      bfv[i] = *(const s16x8*)(Br + (wn + i * 16 + l15) * 32 + ((g ^ q2) * 8));
#pragma unroll
    for (int mi = 0; mi < 4; ++mi)
#pragma unroll
      for (int ni = 0; ni < 4; ++ni)
        acc[mi][ni] = mfma_bf16(af[mi], bfv[ni], acc[mi][ni]);
    __syncthreads();
  }

  float bi[4];
#pragma unroll
  for (int ni = 0; ni < 4; ++ni) bi[ni] = bias[n0 + wn + ni * 16 + l15];
#pragma unroll
  for (int mi = 0; mi < 4; ++mi)
#pragma unroll
    for (int r = 0; r < 4; ++r)
#pragma unroll
      for (int ni = 0; ni < 4; ++ni)
        out[(size_t)(m0 + wm + mi * 16 + g * 4 + r) * 1024 + n0 + wn + ni * 16 + l15] =
            acc[mi][ni][r] + bi[ni];
}

// ---------------------------------------------------------------------------
extern "C" void kernel_launch(void* const* d_in, const int* in_sizes, int n_in,
                              void* d_out, int out_size, void* d_ws, size_t ws_size,
                              hipStream_t stream) {
  const float* x     = (const float*)d_in[0];
  const int*   mask  = (const int*)d_in[1];    // padding_mask (bool -> int32)
  const float* alibi = (const float*)d_in[2];
  const float* qkvw  = (const float*)d_in[3];
  const float* projw = (const float*)d_in[4];
  const float* projb = (const float*)d_in[5];
  const float* lsc   = (const float*)d_in[6];

  char* ws = (char*)d_ws;                       // 48 MB used
  bh16* xb  = (bh16*)(ws);                      //  8 MB  x bf16 [4096][1024]
  bh16* wqb = (bh16*)(ws + 8388608);            //  6 MB  qkv_w bf16 [3072][1024]
  bh16* wpb = (bh16*)(ws + 14680064);           //  2 MB  proj_w bf16 [1024][1024]
  bh16* Qn  = (bh16*)(ws + 16777216);           //  8 MB  normalized Q [bh][n][d]
  bh16* Kn  = (bh16*)(ws + 25165824);           //  8 MB  normalized K [bh][n][d]
  bh16* Vt  = (bh16*)(ws + 33554432);           //  8 MB  V^T [bh][d][n]
  bh16* ao  = (bh16*)(ws + 41943040);           //  8 MB  attn out [b][n][h*64+d]

  // mbits: 512 B of mask bit-words. ws tail if present, else d_out tail
  // (written by cast, read by attn, clobbered only by proj afterwards).
  uint32_t* mbits;
  if (ws_size >= 50331648 + 512) mbits = (uint32_t*)(ws + 50331648);
  else                           mbits = (uint32_t*)((char*)d_out + out_size - 512);

  cast_kernel<<<8193, 256, 0, stream>>>(x, qkvw, projw, mask, xb, wqb, wpb, mbits);
  qkv_kernel<<<768, 256, 0, stream>>>(xb, wqb, Qn, Kn, Vt);
  attn_kernel<<<1024, 256, 0, stream>>>(Qn, Kn, Vt, alibi, mbits, lsc, ao);
  proj_kernel<<<256, 256, 0, stream>>>(ao, wpb, projb, (float*)d_out);
}